// Round 5
// baseline (474.036 us; speedup 1.0000x reference)
//
#include <hip/hip_runtime.h>
#include <stdint.h>

typedef float f32x4 __attribute__((ext_vector_type(4)));
typedef short s16x8 __attribute__((ext_vector_type(8)));
typedef unsigned u32x4 __attribute__((ext_vector_type(4)));

#define B_SZ 256
#define A_RG 196
#define DVD  2048
#define RNN  1024
#define H_SZ 512
#define M_TOT (B_SZ * A_RG)   // 50176 flat rows
#define BM 64
#define BK 32
#define KT (DVD / BK)         // 64

__device__ __forceinline__ unsigned short f2bf(float f) {
    unsigned u = __builtin_bit_cast(unsigned, f);
    u = u + 0x7FFFu + ((u >> 16) & 1u);   // RNE
    return (unsigned short)(u >> 16);
}

__device__ __forceinline__ unsigned cvt2(float a, float b) {
    unsigned r;
    asm("v_cvt_pk_bf16_f32 %0, %1, %2" : "=v"(r) : "v"(a), "v"(b));
    return r;
}

// ---------------------------------------------------------------------------
// Kernel 1: W_v [2048,512] fp32 -> Wt [512,2048] bf16 (plain transpose,
// k-contiguous per column; B-fragments are read directly from L2).
// ---------------------------------------------------------------------------
__global__ __launch_bounds__(256) void k_prepW(const float* __restrict__ Wv,
                                               unsigned short* __restrict__ Wt) {
    __shared__ float tile[64][65];
    int kt = blockIdx.x >> 3, ct = blockIdx.x & 7;
    int k0 = kt * 64, c0 = ct * 64;
    int t = threadIdx.x;
    int cl = t & 63, rq = t >> 6;
#pragma unroll
    for (int i = 0; i < 16; ++i) {
        int r = rq * 16 + i;
        tile[r][cl] = Wv[(size_t)(k0 + r) * H_SZ + c0 + cl];
    }
    __syncthreads();
    int kl = t & 63;
#pragma unroll
    for (int i = 0; i < 16; ++i) {
        int cr = rq * 16 + i;
        Wt[(size_t)(c0 + cr) * DVD + k0 + kl] = f2bf(tile[kl][cr]);
    }
}

// ---------------------------------------------------------------------------
// Kernel 2: base[b,h] = h_att[b]@W_ha + prev_h2[b]@W_hv + b_ha + b_hv + b_v
// ---------------------------------------------------------------------------
__global__ __launch_bounds__(256) void k_base(const float* __restrict__ h_att,
                                              const float* __restrict__ prev_h2,
                                              const float* __restrict__ W_ha,
                                              const float* __restrict__ b_ha,
                                              const float* __restrict__ W_hv,
                                              const float* __restrict__ b_hv,
                                              const float* __restrict__ b_v,
                                              float* __restrict__ base_g) {
    __shared__ float ha_s[4][RNN];
    __shared__ float pv_s[4][RNN];
    int bg = blockIdx.x >> 2, hg = blockIdx.x & 3;
    int t = threadIdx.x;
#pragma unroll
    for (int i = 0; i < 16; ++i) {
        int idx = i * 256 + t;
        int bl = idx >> 10, k = idx & 1023;
        ha_s[bl][k] = h_att[(size_t)(bg * 4 + bl) * RNN + k];
        pv_s[bl][k] = prev_h2[(size_t)(bg * 4 + bl) * RNN + k];
    }
    __syncthreads();
    int h = hg * 128 + (t & 127);
    int br = t >> 7;
    float aA0 = 0, aA1 = 0, aV0 = 0, aV1 = 0;
#pragma unroll 4
    for (int k = 0; k < RNN; ++k) {
        float w1 = W_ha[(size_t)k * H_SZ + h];
        float w2 = W_hv[(size_t)k * H_SZ + h];
        aA0 = fmaf(ha_s[br * 2][k],     w1, aA0);
        aA1 = fmaf(ha_s[br * 2 + 1][k], w1, aA1);
        aV0 = fmaf(pv_s[br * 2][k],     w2, aV0);
        aV1 = fmaf(pv_s[br * 2 + 1][k], w2, aV1);
    }
    float bias = b_ha[h] + b_hv[h] + b_v[h];
    base_g[(size_t)(bg * 4 + br * 2) * H_SZ + h]     = aA0 + aV0 + bias;
    base_g[(size_t)(bg * 4 + br * 2 + 1) * H_SZ + h] = aA1 + aV1 + bias;
}

// ---------------------------------------------------------------------------
// Kernel 3: flat-M GEMM [50176,2048]x[2048,512] -> fused relu(.+base)*W_f
// reduce -> att_g. BM=64, 256 threads (4 waves, each 64 rows x 128 cols,
// acc[4][8] = 128 AGPR). B fragments stream directly from L2 (Wt = 2MB,
// L2-resident) into a 2-tile register pipeline; LDS holds only A
// (2 x 4KB bf16, XOR-swizzled slot = chunk ^ ((r^(r>>2))&3): conflict-free).
// One raw s_barrier per K-step, never vmcnt(0). 2 blocks/CU co-resident.
// ---------------------------------------------------------------------------
__global__ __launch_bounds__(256, 2) void k_gemm(const float* __restrict__ imgs,
                                                 const unsigned short* __restrict__ Wt,
                                                 const float* __restrict__ base_g,
                                                 const float* __restrict__ W_f,
                                                 float* __restrict__ att_g) {
    __shared__ __align__(16) short A_s[2][BM * BK];   // 2 x 4 KB
    __shared__ float wf_s[H_SZ];
    __shared__ float base_s[2][H_SZ];
    __shared__ float att_part[4][BM];

    const int m0 = blockIdx.x * BM;
    const int t = threadIdx.x;
    const int lane = t & 63, w = t >> 6;
    const int b0 = m0 / A_RG;
    const int b1 = min(b0 + 1, B_SZ - 1);

    wf_s[t] = W_f[t];
    wf_s[t + 256] = W_f[t + 256];
    base_s[0][t]       = base_g[(size_t)b0 * H_SZ + t];
    base_s[0][t + 256] = base_g[(size_t)b0 * H_SZ + t + 256];
    base_s[1][t]       = base_g[(size_t)b1 * H_SZ + t];
    base_s[1][t + 256] = base_g[(size_t)b1 * H_SZ + t + 256];

    // ---- A staging map: thread -> row t>>2, chunk t&3 (8 floats) ----
    const int arow = t >> 2, ac = t & 3;
    const float* Ag = imgs + (size_t)(m0 + arow) * DVD + ac * 8;
    const unsigned awr =
        (unsigned)(arow * 64 + ((ac ^ ((arow ^ (arow >> 2)) & 3)) * 16));

    // ---- A fragment read addresses ----
    const int lr = lane & 15, g = lane >> 4;
    unsigned ard[4];
#pragma unroll
    for (int m = 0; m < 4; ++m) {
        int r = m * 16 + lr;
        ard[m] = (unsigned)(r * 64 + ((g ^ ((r ^ (r >> 2)) & 3)) * 16));
    }

    // ---- B fragment byte offsets (32-bit, Wt = 2MB) ----
    const char* Wb = (const char*)Wt;
    unsigned bof[8];
#pragma unroll
    for (int n = 0; n < 8; ++n)
        bof[n] = (unsigned)((w * 128 + n * 16 + lr) * (DVD * 2) + g * 16);

    f32x4 acc[4][8] = {};
    float4 aR[2][2];
    s16x8 bR[2][8];

    auto ldA = [&](int p, int kt) {
        const float4* q = (const float4*)(Ag + kt * BK);
        aR[p][0] = q[0];
        aR[p][1] = q[1];
    };
    auto ldB = [&](int p, int kt) {
#pragma unroll
        for (int n = 0; n < 8; ++n)
            bR[p][n] = *(const s16x8*)(Wb + bof[n] + (unsigned)kt * 64);
    };
    auto wrA = [&](int p, int buf) {
        float4 lo = aR[p][0], hi = aR[p][1];
        u32x4 pk;
        pk[0] = cvt2(lo.x, lo.y);
        pk[1] = cvt2(lo.z, lo.w);
        pk[2] = cvt2(hi.x, hi.y);
        pk[3] = cvt2(hi.z, hi.w);
        *(s16x8*)((char*)A_s[buf] + awr) = __builtin_bit_cast(s16x8, pk);
    };
    auto mfmaStep = [&](int P) {
        const char* Ab = (const char*)A_s[P];
        s16x8 af[4];
#pragma unroll
        for (int m = 0; m < 4; ++m) af[m] = *(const s16x8*)(Ab + ard[m]);
        __builtin_amdgcn_s_setprio(1);
#pragma unroll
        for (int m = 0; m < 4; ++m)
#pragma unroll
            for (int n = 0; n < 8; ++n)
                acc[m][n] = __builtin_amdgcn_mfma_f32_16x16x32_bf16(
                    af[m], bR[P][n], acc[m][n], 0, 0, 0);
        __builtin_amdgcn_s_setprio(0);
    };
    auto fence = [&]() {
        __builtin_amdgcn_sched_barrier(0);
        asm volatile("s_waitcnt lgkmcnt(0)" ::: "memory");
        __builtin_amdgcn_s_barrier();
    };

    // ---- prologue: tiles 0,1 in flight; tile 0 into LDS buf0 ----
    ldA(0, 0); ldB(0, 0);
    ldA(1, 1); ldB(1, 1);
    wrA(0, 0);                 // auto vmcnt wait for A(0) only
    fence();

    // ---- main loop: phase P computes tile kt, stages kt+2, writes kt+1 ----
    for (int kt = 0; kt < KT - 2; kt += 2) {
        // P = 0
        ldA(0, kt + 2);
        mfmaStep(0);
        wrA(1, 1);             // tile kt+1 -> buf1 (readers synced last fence)
        ldB(0, kt + 2);
        fence();
        // P = 1
        ldA(1, kt + 3);
        mfmaStep(1);
        wrA(0, 0);             // tile kt+2 -> buf0
        ldB(1, kt + 3);
        fence();
    }
    // kt = 62: compute buf0, write tile 63 -> buf1
    mfmaStep(0);
    wrA(1, 1);
    fence();
    // kt = 63
    mfmaStep(1);

    // ---- epilogue: att[row] = sum_h relu(p + base[b(row),h]) * W_f[h] ----
#pragma unroll
    for (int m = 0; m < 4; ++m) {
        float pj[4] = {0.f, 0.f, 0.f, 0.f};
#pragma unroll
        for (int n = 0; n < 8; ++n) {
            int col = w * 128 + n * 16 + lr;
            float wfv = wf_s[col];
            f32x4 a4 = acc[m][n];
#pragma unroll
            for (int j = 0; j < 4; ++j) {
                int row = m * 16 + g * 4 + j;
                int bi = (m0 + row) / A_RG - b0;     // 0 or 1
                pj[j] += fmaxf(a4[j] + base_s[bi][col], 0.f) * wfv;
            }
        }
#pragma unroll
        for (int j = 0; j < 4; ++j) {
            float s = pj[j];
            s += __shfl_xor(s, 1);
            s += __shfl_xor(s, 2);
            s += __shfl_xor(s, 4);
            s += __shfl_xor(s, 8);     // sum over the 16 lr-lanes of this row
            if (lr == 0) {
                int row = m * 16 + g * 4 + j;
                att_part[w][row] = s;  // unique writer per (w,row)
            }
        }
    }
    __syncthreads();

    if (t < BM) {
        att_g[m0 + t] = att_part[0][t] + att_part[1][t] +
                        att_part[2][t] + att_part[3][t];
    }
}

// ---------------------------------------------------------------------------
// Kernel 4: softmax over A=196 + weighted sum. One block per b, 1024 threads,
// thread t owns cols {2t, 2t+1}.
// ---------------------------------------------------------------------------
__global__ __launch_bounds__(1024) void k_ws(const float* __restrict__ imgs,
                                             const float* __restrict__ att_g,
                                             float* __restrict__ out) {
    __shared__ float alpha_s[A_RG];
    int b = blockIdx.x;
    int t = threadIdx.x;

    if (t < 64) {
        float v[4], e[4];
        float mx = -1e30f;
#pragma unroll
        for (int i = 0; i < 4; ++i) {
            int r = i * 64 + t;
            v[i] = (r < A_RG) ? att_g[(size_t)b * A_RG + r] : -1e30f;
            mx = fmaxf(mx, v[i]);
        }
        for (int d = 1; d < 64; d <<= 1) mx = fmaxf(mx, __shfl_xor(mx, d));
        float sum = 0.f;
#pragma unroll
        for (int i = 0; i < 4; ++i) {
            int r = i * 64 + t;
            e[i] = (r < A_RG) ? __expf(v[i] - mx) : 0.f;
            sum += e[i];
        }
        for (int d = 1; d < 64; d <<= 1) sum += __shfl_xor(sum, d);
        float inv = 1.0f / sum;
#pragma unroll
        for (int i = 0; i < 4; ++i) {
            int r = i * 64 + t;
            if (r < A_RG) alpha_s[r] = e[i] * inv;
        }
    }
    __syncthreads();

    const float2* ib2 = (const float2*)(imgs + (size_t)b * A_RG * DVD) + t;
    float2 o0 = make_float2(0.f, 0.f), o1 = make_float2(0.f, 0.f);
#pragma unroll 2
    for (int a = 0; a < A_RG; a += 2) {
        float al0 = alpha_s[a], al1 = alpha_s[a + 1];
        float2 v0 = ib2[(size_t)a * (DVD / 2)];
        float2 v1 = ib2[(size_t)(a + 1) * (DVD / 2)];
        o0.x = fmaf(al0, v0.x, o0.x);
        o0.y = fmaf(al0, v0.y, o0.y);
        o1.x = fmaf(al1, v1.x, o1.x);
        o1.y = fmaf(al1, v1.y, o1.y);
    }
    float2 o = make_float2(o0.x + o1.x, o0.y + o1.y);
    ((float2*)out)[(size_t)b * (DVD / 2) + t] = o;
}

// ---------------------------------------------------------------------------
extern "C" void kernel_launch(void* const* d_in, const int* in_sizes, int n_in,
                              void* d_out, int out_size, void* d_ws, size_t ws_size,
                              hipStream_t stream) {
    const float* h_att   = (const float*)d_in[0];
    const float* prev_h2 = (const float*)d_in[1];
    const float* imgs    = (const float*)d_in[2];
    const float* W_v     = (const float*)d_in[3];
    const float* b_v     = (const float*)d_in[4];
    const float* W_ha    = (const float*)d_in[5];
    const float* b_ha    = (const float*)d_in[6];
    const float* W_hv    = (const float*)d_in[7];
    const float* b_hv    = (const float*)d_in[8];
    const float* W_f     = (const float*)d_in[9];
    // d_in[10] = b_f: softmax-invariant additive constant -> unused

    // ws layout: [0,2MB) Wt bf16 [512][2048]; [2MB,+512KB) base fp32 [256][512];
    //            then att fp32 [50176]
    unsigned short* Wt = (unsigned short*)d_ws;
    float* base_g = (float*)((char*)d_ws + (size_t)DVD * H_SZ * 2);
    float* att_g  = (float*)((char*)d_ws + (size_t)DVD * H_SZ * 2 + (size_t)B_SZ * H_SZ * 4);
    float* out = (float*)d_out;

    hipLaunchKernelGGL(k_prepW, dim3(256), dim3(256), 0, stream, W_v, Wt);
    hipLaunchKernelGGL(k_base, dim3(256), dim3(256), 0, stream,
                       h_att, prev_h2, W_ha, b_ha, W_hv, b_hv, b_v, base_g);
    hipLaunchKernelGGL(k_gemm, dim3(M_TOT / BM), dim3(256), 0, stream,
                       imgs, Wt, base_g, W_f, att_g);
    hipLaunchKernelGGL(k_ws, dim3(B_SZ), dim3(1024), 0, stream,
                       imgs, att_g, out);
}

// Round 6
// 372.716 us; speedup vs baseline: 1.2718x; 1.2718x over previous
//
#include <hip/hip_runtime.h>
#include <stdint.h>

typedef float f32x4 __attribute__((ext_vector_type(4)));
typedef short s16x8 __attribute__((ext_vector_type(8)));
typedef unsigned u32x4 __attribute__((ext_vector_type(4)));

#define B_SZ 256
#define A_RG 196
#define DVD  2048
#define RNN  1024
#define H_SZ 512
#define M_TOT (B_SZ * A_RG)   // 50176 flat rows
#define BM 64
#define BK 32
#define KT (DVD / BK)         // 64

__device__ __forceinline__ unsigned short f2bf(float f) {
    unsigned u = __builtin_bit_cast(unsigned, f);
    u = u + 0x7FFFu + ((u >> 16) & 1u);   // RNE
    return (unsigned short)(u >> 16);
}

__device__ __forceinline__ unsigned cvt2(float a, float b) {
    unsigned r;
    asm("v_cvt_pk_bf16_f32 %0, %1, %2" : "=v"(r) : "v"(a), "v"(b));
    return r;
}

__device__ __forceinline__ void gll16(const void* g, void* l) {
    __builtin_amdgcn_global_load_lds(
        (const __attribute__((address_space(1))) void*)g,
        (__attribute__((address_space(3))) void*)l, 16, 0, 0);
}

// ---------------------------------------------------------------------------
// Kernel 1: W_v [2048,512] fp32 -> Wt2 bf16, K-TILE-MAJOR: Wt2[kt][col][32k],
// so one K-step's B tile is a contiguous 32KB slab (coalesced gll staging).
// Within each col's 64B row, 16B chunk c stored at c ^ ((col>>1)&3) so the
// linear LDS copy lands in the bank-conflict-free read layout.
// ---------------------------------------------------------------------------
__global__ __launch_bounds__(256) void k_prepW(const float* __restrict__ Wv,
                                               unsigned short* __restrict__ Wt2) {
    __shared__ float tile[64][65];
    int kt = blockIdx.x >> 3, ct = blockIdx.x & 7;
    int k0 = kt * 64, c0 = ct * 64;
    int t = threadIdx.x;
    int cl = t & 63, rq = t >> 6;
#pragma unroll
    for (int i = 0; i < 16; ++i) {
        int r = rq * 16 + i;
        tile[r][cl] = Wv[(size_t)(k0 + r) * H_SZ + c0 + cl];
    }
    __syncthreads();
    int kl = t & 63;
#pragma unroll
    for (int i = 0; i < 16; ++i) {
        int cr = rq * 16 + i;
        int col = c0 + cr;
        int k = k0 + kl;
        int sw = (col >> 1) & 3;
        size_t dst = (size_t)(k >> 5) * (H_SZ * 32)
                   + (size_t)col * 32
                   + ((((k >> 3) & 3) ^ sw) * 8) + (k & 7);
        Wt2[dst] = f2bf(tile[kl][cr]);
    }
}

// ---------------------------------------------------------------------------
// Kernel 2: base[b,h] = h_att[b]@W_ha + prev_h2[b]@W_hv + b_ha + b_hv + b_v
// ---------------------------------------------------------------------------
__global__ __launch_bounds__(256) void k_base(const float* __restrict__ h_att,
                                              const float* __restrict__ prev_h2,
                                              const float* __restrict__ W_ha,
                                              const float* __restrict__ b_ha,
                                              const float* __restrict__ W_hv,
                                              const float* __restrict__ b_hv,
                                              const float* __restrict__ b_v,
                                              float* __restrict__ base_g) {
    __shared__ float ha_s[4][RNN];
    __shared__ float pv_s[4][RNN];
    int bg = blockIdx.x >> 2, hg = blockIdx.x & 3;
    int t = threadIdx.x;
#pragma unroll
    for (int i = 0; i < 16; ++i) {
        int idx = i * 256 + t;
        int bl = idx >> 10, k = idx & 1023;
        ha_s[bl][k] = h_att[(size_t)(bg * 4 + bl) * RNN + k];
        pv_s[bl][k] = prev_h2[(size_t)(bg * 4 + bl) * RNN + k];
    }
    __syncthreads();
    int h = hg * 128 + (t & 127);
    int br = t >> 7;
    float aA0 = 0, aA1 = 0, aV0 = 0, aV1 = 0;
#pragma unroll 4
    for (int k = 0; k < RNN; ++k) {
        float w1 = W_ha[(size_t)k * H_SZ + h];
        float w2 = W_hv[(size_t)k * H_SZ + h];
        aA0 = fmaf(ha_s[br * 2][k],     w1, aA0);
        aA1 = fmaf(ha_s[br * 2 + 1][k], w1, aA1);
        aV0 = fmaf(pv_s[br * 2][k],     w2, aV0);
        aV1 = fmaf(pv_s[br * 2 + 1][k], w2, aV1);
    }
    float bias = b_ha[h] + b_hv[h] + b_v[h];
    base_g[(size_t)(bg * 4 + br * 2) * H_SZ + h]     = aA0 + aV0 + bias;
    base_g[(size_t)(bg * 4 + br * 2 + 1) * H_SZ + h] = aA1 + aV1 + bias;
}

// ---------------------------------------------------------------------------
// Kernel 3: flat-M GEMM [50176,2048]x[2048,512] -> fused relu(.+base)*W_f
// reduce -> att_g. BM=64, 512 threads = 8 waves (2M x 4N, wave 32x128,
// acc[2][8] = 64 regs). All staging via global_load_lds: A fp32 dbuf
// (src pre-swizzled, cvt at frag read), B bf16 single-buffer from contiguous
// K-tile-major Wt2 (L2-resident). 2 raw barriers/step, counted vmcnt(1).
// LDS 49KB, <=128 regs -> 2 blocks/CU (16 waves).
// ---------------------------------------------------------------------------
__global__ __launch_bounds__(512, 4) void k_gemm(const float* __restrict__ imgs,
                                                 const unsigned short* __restrict__ Wt2,
                                                 const float* __restrict__ base_g,
                                                 const float* __restrict__ W_f,
                                                 float* __restrict__ att_g) {
    __shared__ __align__(16) float A_s[2][BM * BK];   // 2 x 8 KB fp32, swizzled
    __shared__ __align__(16) short B_s[H_SZ * BK];    // 32 KB bf16, swizzled
    __shared__ float att_part[4][BM];

    const int m0 = blockIdx.x * BM;
    const int t = threadIdx.x;
    const int lane = t & 63, w = t >> 6;

    // ---- A gll source: wave w stages rows w*8..w*8+7 (1KB = 1 gll) ----
    // lane -> row w*8 + (lane>>3), src chunk (lane&7)^(lane>>3) (pre-swizzle
    // so LDS chunk c of row r holds global chunk c^(r&7), r&7 == lane>>3).
    const char* Asrc = (const char*)(imgs + (size_t)(m0 + w * 8 + (lane >> 3)) * DVD)
                     + ((lane & 7) ^ (lane >> 3)) * 16;
    const unsigned AldsOff = (unsigned)(w * 1024 + lane * 16);
    // ---- B gll source: contiguous 32KB per K-tile ----
    const char* Bsrc = (const char*)Wt2 + (size_t)w * 4096 + (size_t)lane * 16;
    const unsigned BldsOff = (unsigned)(w * 4096 + lane * 16);

    auto stageA = [&](int buf, int kt) {
        gll16(Asrc + (size_t)kt * 128, (char*)A_s[buf] + AldsOff);
    };
    auto stageB = [&](int kt) {
        const char* s = Bsrc + (size_t)kt * 32768;
        char* d = (char*)B_s + BldsOff;
#pragma unroll
        for (int i = 0; i < 4; ++i)
            gll16(s + i * 1024, d + i * 1024);
    };

    // ---- fragment read addresses ----
    const int wm = w >> 2, wn = w & 3;          // 2M x 4N wave grid
    const int lr = lane & 15, g = lane >> 4;
    unsigned aLo[2], aHi[2], bAddr[8];
#pragma unroll
    for (int m = 0; m < 2; ++m) {
        int r = wm * 32 + m * 16 + lr;
        aLo[m] = (unsigned)(r * 128 + (((2 * g) ^ (r & 7)) * 16));
        aHi[m] = (unsigned)(r * 128 + (((2 * g + 1) ^ (r & 7)) * 16));
    }
#pragma unroll
    for (int n = 0; n < 8; ++n) {
        int c = wn * 128 + n * 16 + lr;
        bAddr[n] = (unsigned)(c * 64 + ((g ^ ((c >> 1) & 3)) * 16));
    }

    f32x4 acc[2][8] = {};

    auto compute = [&](int buf) {
        const char* Ac = (const char*)A_s[buf];
        const char* Bc = (const char*)B_s;
        s16x8 af[2];
#pragma unroll
        for (int m = 0; m < 2; ++m) {
            f32x4 lo = *(const f32x4*)(Ac + aLo[m]);
            f32x4 hi = *(const f32x4*)(Ac + aHi[m]);
            u32x4 p;
            p[0] = cvt2(lo[0], lo[1]);
            p[1] = cvt2(lo[2], lo[3]);
            p[2] = cvt2(hi[0], hi[1]);
            p[3] = cvt2(hi[2], hi[3]);
            af[m] = __builtin_bit_cast(s16x8, p);
        }
        // two n-halves to cap live B fragments at 4 (register budget)
#pragma unroll
        for (int h = 0; h < 2; ++h) {
            s16x8 bfr[4];
#pragma unroll
            for (int n = 0; n < 4; ++n)
                bfr[n] = *(const s16x8*)(Bc + bAddr[h * 4 + n]);
            __builtin_amdgcn_s_setprio(1);
#pragma unroll
            for (int m = 0; m < 2; ++m)
#pragma unroll
                for (int n = 0; n < 4; ++n)
                    acc[m][h * 4 + n] = __builtin_amdgcn_mfma_f32_16x16x32_bf16(
                        af[m], bfr[n], acc[m][h * 4 + n], 0, 0, 0);
            __builtin_amdgcn_s_setprio(0);
        }
    };

    // ---- prologue: B(0), A(0), A(1) in flight; wait all but A(1) ----
    stageB(0);
    stageA(0, 0);
    stageA(1, 1);
    asm volatile("s_waitcnt vmcnt(1)" ::: "memory");
    __builtin_amdgcn_sched_barrier(0);
    __builtin_amdgcn_s_barrier();

    for (int kt = 0; kt < KT; ++kt) {
        compute(kt & 1);
        asm volatile("" ::: "memory");
        __builtin_amdgcn_s_barrier();           // all reads of B / A[kt&1] done
        if (kt < KT - 1) stageB(kt + 1);
        if (kt < KT - 2) {
            stageA(kt & 1, kt + 2);             // buf (kt+2)&1 == kt&1
            asm volatile("s_waitcnt vmcnt(1)" ::: "memory");  // A(kt+1),B(kt+1) done
        } else if (kt < KT - 1) {
            asm volatile("s_waitcnt vmcnt(0)" ::: "memory");
        }
        __builtin_amdgcn_sched_barrier(0);
        __builtin_amdgcn_s_barrier();           // staged tile visible
    }

    // ---- epilogue: att[row] = sum_h relu(p + base[b(row),h]) * W_f[h] ----
    const int b0 = m0 / A_RG;
    const int b1 = min(b0 + 1, B_SZ - 1);
    float wfv[8], bs0[8], bs1[8];
#pragma unroll
    for (int n = 0; n < 8; ++n) {
        int col = wn * 128 + n * 16 + lr;
        wfv[n] = W_f[col];
        bs0[n] = base_g[(size_t)b0 * H_SZ + col];
        bs1[n] = base_g[(size_t)b1 * H_SZ + col];
    }
#pragma unroll
    for (int m = 0; m < 2; ++m) {
        float pj[4] = {0.f, 0.f, 0.f, 0.f};
#pragma unroll
        for (int j = 0; j < 4; ++j) {
            int row = wm * 32 + m * 16 + g * 4 + j;
            bool second = (m0 + row) >= (b0 + 1) * A_RG;
#pragma unroll
            for (int n = 0; n < 8; ++n) {
                float bsv = second ? bs1[n] : bs0[n];
                pj[j] += fmaxf(acc[m][n][j] + bsv, 0.f) * wfv[n];
            }
        }
#pragma unroll
        for (int j = 0; j < 4; ++j) {
            float s = pj[j];
            s += __shfl_xor(s, 1);
            s += __shfl_xor(s, 2);
            s += __shfl_xor(s, 4);
            s += __shfl_xor(s, 8);     // sum over the 16 lr-lanes of this row
            if (lr == 0) {
                int row = wm * 32 + m * 16 + g * 4 + j;
                att_part[wn][row] = s;  // unique writer per (wn,row)
            }
        }
    }
    __syncthreads();

    if (t < BM) {
        att_g[m0 + t] = att_part[0][t] + att_part[1][t] +
                        att_part[2][t] + att_part[3][t];
    }
}

// ---------------------------------------------------------------------------
// Kernel 4: softmax over A=196 + weighted sum. grid (2 d-halves, 256 b),
// block 256; thread t owns one f32x4 column group (1KB/wave coalesced).
// ---------------------------------------------------------------------------
__global__ __launch_bounds__(256) void k_ws(const float* __restrict__ imgs,
                                            const float* __restrict__ att_g,
                                            float* __restrict__ out) {
    __shared__ float alpha_s[A_RG];
    int b = blockIdx.y, dc = blockIdx.x;
    int t = threadIdx.x;

    if (t < 64) {
        float v[4], e[4];
        float mx = -1e30f;
#pragma unroll
        for (int i = 0; i < 4; ++i) {
            int r = i * 64 + t;
            v[i] = (r < A_RG) ? att_g[(size_t)b * A_RG + r] : -1e30f;
            mx = fmaxf(mx, v[i]);
        }
        for (int d = 1; d < 64; d <<= 1) mx = fmaxf(mx, __shfl_xor(mx, d));
        float sum = 0.f;
#pragma unroll
        for (int i = 0; i < 4; ++i) {
            int r = i * 64 + t;
            e[i] = (r < A_RG) ? __expf(v[i] - mx) : 0.f;
            sum += e[i];
        }
        for (int d = 1; d < 64; d <<= 1) sum += __shfl_xor(sum, d);
        float inv = 1.0f / sum;
#pragma unroll
        for (int i = 0; i < 4; ++i) {
            int r = i * 64 + t;
            if (r < A_RG) alpha_s[r] = e[i] * inv;
        }
    }
    __syncthreads();

    const float* ib = imgs + (size_t)b * A_RG * DVD + dc * 1024 + t * 4;
    f32x4 o0 = {}, o1 = {};
#pragma unroll 2
    for (int a = 0; a < A_RG; a += 2) {
        float al0 = alpha_s[a], al1 = alpha_s[a + 1];
        f32x4 v0 = *(const f32x4*)(ib + (size_t)a * DVD);
        f32x4 v1 = *(const f32x4*)(ib + (size_t)(a + 1) * DVD);
#pragma unroll
        for (int j = 0; j < 4; ++j) {
            o0[j] = fmaf(al0, v0[j], o0[j]);
            o1[j] = fmaf(al1, v1[j], o1[j]);
        }
    }
    f32x4 o;
#pragma unroll
    for (int j = 0; j < 4; ++j) o[j] = o0[j] + o1[j];
    *(f32x4*)(out + (size_t)b * DVD + dc * 1024 + t * 4) = o;
}

// ---------------------------------------------------------------------------
extern "C" void kernel_launch(void* const* d_in, const int* in_sizes, int n_in,
                              void* d_out, int out_size, void* d_ws, size_t ws_size,
                              hipStream_t stream) {
    const float* h_att   = (const float*)d_in[0];
    const float* prev_h2 = (const float*)d_in[1];
    const float* imgs    = (const float*)d_in[2];
    const float* W_v     = (const float*)d_in[3];
    const float* b_v     = (const float*)d_in[4];
    const float* W_ha    = (const float*)d_in[5];
    const float* b_ha    = (const float*)d_in[6];
    const float* W_hv    = (const float*)d_in[7];
    const float* b_hv    = (const float*)d_in[8];
    const float* W_f     = (const float*)d_in[9];
    // d_in[10] = b_f: softmax-invariant additive constant -> unused

    // ws layout: [0,2MB) Wt2 bf16 [64][512][32] (k-tile-major, pre-swizzled);
    //            [2MB,+512KB) base fp32 [256][512]; then att fp32 [50176]
    unsigned short* Wt2 = (unsigned short*)d_ws;
    float* base_g = (float*)((char*)d_ws + (size_t)DVD * H_SZ * 2);
    float* att_g  = (float*)((char*)d_ws + (size_t)DVD * H_SZ * 2 + (size_t)B_SZ * H_SZ * 4);
    float* out = (float*)d_out;

    hipLaunchKernelGGL(k_prepW, dim3(256), dim3(256), 0, stream, W_v, Wt2);
    hipLaunchKernelGGL(k_base, dim3(256), dim3(256), 0, stream,
                       h_att, prev_h2, W_ha, b_ha, W_hv, b_hv, b_v, base_g);
    hipLaunchKernelGGL(k_gemm, dim3(M_TOT / BM), dim3(512), 0, stream,
                       imgs, Wt2, base_g, W_f, att_g);
    hipLaunchKernelGGL(k_ws, dim3(2, B_SZ), dim3(256), 0, stream,
                       imgs, att_g, out);
}

// Round 7
// 365.310 us; speedup vs baseline: 1.2976x; 1.0203x over previous
//
#include <hip/hip_runtime.h>
#include <stdint.h>

typedef float f32x4 __attribute__((ext_vector_type(4)));
typedef short s16x8 __attribute__((ext_vector_type(8)));
typedef unsigned u32x2 __attribute__((ext_vector_type(2)));

#define B_SZ 256
#define A_RG 196
#define DVD  2048
#define RNN  1024
#define H_SZ 512
#define M_TOT (B_SZ * A_RG)   // 50176 flat rows
#define BM 64
#define BK 32
#define KT (DVD / BK)         // 64

__device__ __forceinline__ unsigned short f2bf(float f) {
    unsigned u = __builtin_bit_cast(unsigned, f);
    u = u + 0x7FFFu + ((u >> 16) & 1u);   // RNE
    return (unsigned short)(u >> 16);
}

__device__ __forceinline__ unsigned cvt2(float a, float b) {
    unsigned r;
    asm("v_cvt_pk_bf16_f32 %0, %1, %2" : "=v"(r) : "v"(a), "v"(b));
    return r;
}

__device__ __forceinline__ void gll16(const void* g, void* l) {
    __builtin_amdgcn_global_load_lds(
        (const __attribute__((address_space(1))) void*)g,
        (__attribute__((address_space(3))) void*)l, 16, 0, 0);
}

// ---------------------------------------------------------------------------
// Kernel 1: W_v [2048,512] fp32 -> Wt2 bf16, K-TILE-MAJOR: Wt2[kt][col][32k],
// one K-step's B tile = contiguous 32KB slab (coalesced gll staging). Within
// each col's 64B row, 16B chunk c stored at c ^ ((col>>1)&3) (pre-swizzle
// matching the conflict-free ds_read pattern).
// ---------------------------------------------------------------------------
__global__ __launch_bounds__(256) void k_prepW(const float* __restrict__ Wv,
                                               unsigned short* __restrict__ Wt2) {
    __shared__ float tile[64][65];
    int kt = blockIdx.x >> 3, ct = blockIdx.x & 7;
    int k0 = kt * 64, c0 = ct * 64;
    int t = threadIdx.x;
    int cl = t & 63, rq = t >> 6;
#pragma unroll
    for (int i = 0; i < 16; ++i) {
        int r = rq * 16 + i;
        tile[r][cl] = Wv[(size_t)(k0 + r) * H_SZ + c0 + cl];
    }
    __syncthreads();
    int kl = t & 63;
#pragma unroll
    for (int i = 0; i < 16; ++i) {
        int cr = rq * 16 + i;
        int col = c0 + cr;
        int k = k0 + kl;
        int sw = (col >> 1) & 3;
        size_t dst = (size_t)(k >> 5) * (H_SZ * 32)
                   + (size_t)col * 32
                   + ((((k >> 3) & 3) ^ sw) * 8) + (k & 7);
        Wt2[dst] = f2bf(tile[kl][cr]);
    }
}

// ---------------------------------------------------------------------------
// Kernel 2: base[b,h] = h_att[b]@W_ha + prev_h2[b]@W_hv + b_ha + b_hv + b_v
// ---------------------------------------------------------------------------
__global__ __launch_bounds__(256) void k_base(const float* __restrict__ h_att,
                                              const float* __restrict__ prev_h2,
                                              const float* __restrict__ W_ha,
                                              const float* __restrict__ b_ha,
                                              const float* __restrict__ W_hv,
                                              const float* __restrict__ b_hv,
                                              const float* __restrict__ b_v,
                                              float* __restrict__ base_g) {
    __shared__ float ha_s[4][RNN];
    __shared__ float pv_s[4][RNN];
    int bg = blockIdx.x >> 2, hg = blockIdx.x & 3;
    int t = threadIdx.x;
#pragma unroll
    for (int i = 0; i < 16; ++i) {
        int idx = i * 256 + t;
        int bl = idx >> 10, k = idx & 1023;
        ha_s[bl][k] = h_att[(size_t)(bg * 4 + bl) * RNN + k];
        pv_s[bl][k] = prev_h2[(size_t)(bg * 4 + bl) * RNN + k];
    }
    __syncthreads();
    int h = hg * 128 + (t & 127);
    int br = t >> 7;
    float aA0 = 0, aA1 = 0, aV0 = 0, aV1 = 0;
#pragma unroll 4
    for (int k = 0; k < RNN; ++k) {
        float w1 = W_ha[(size_t)k * H_SZ + h];
        float w2 = W_hv[(size_t)k * H_SZ + h];
        aA0 = fmaf(ha_s[br * 2][k],     w1, aA0);
        aA1 = fmaf(ha_s[br * 2 + 1][k], w1, aA1);
        aV0 = fmaf(pv_s[br * 2][k],     w2, aV0);
        aV1 = fmaf(pv_s[br * 2 + 1][k], w2, aV1);
    }
    float bias = b_ha[h] + b_hv[h] + b_v[h];
    base_g[(size_t)(bg * 4 + br * 2) * H_SZ + h]     = aA0 + aV0 + bias;
    base_g[(size_t)(bg * 4 + br * 2 + 1) * H_SZ + h] = aA1 + aV1 + bias;
}

// ---------------------------------------------------------------------------
// Kernel 3: flat-M GEMM [50176,2048]x[2048,512] -> fused relu(.+base)*W_f
// reduce -> att_g. 512 thr = 8 waves (2M x 4N, wave 32x128, acc[2][8]).
// BOTH operands double-buffered: B via gll (issued at TOP of step, latency
// hides under MFMA), A via reg-staging bf16 (global load 2 steps ahead,
// cvt_pk + ds_write just before compute). ONE barrier per step, counted
// vmcnt(1). LDS 73KB, <=128 regs -> 2 blocks/CU (16 waves).
// ---------------------------------------------------------------------------
__global__ __launch_bounds__(512, 4) void k_gemm(const float* __restrict__ imgs,
                                                 const unsigned short* __restrict__ Wt2,
                                                 const float* __restrict__ base_g,
                                                 const float* __restrict__ W_f,
                                                 float* __restrict__ att_g) {
    __shared__ __align__(16) short A_s[2][BM * BK];    // 2 x 4 KB bf16, swizzled
    __shared__ __align__(16) short B_s[2][H_SZ * BK];  // 2 x 32 KB bf16, swizzled
    __shared__ float att_part[4][BM];

    const int m0 = blockIdx.x * BM;
    const int t = threadIdx.x;
    const int lane = t & 63, w = t >> 6;

    // ---- A load/write map: thread t -> row t>>3, 8B slot t&7 ----
    const int arow = t >> 3, as = t & 7;
    const float* Ag = imgs + (size_t)(m0 + arow) * DVD + as * 4;
    const unsigned awr = (unsigned)(arow * 64
                       + (((as >> 1) ^ ((arow >> 1) & 3)) << 4) + ((as & 1) << 3));

    // ---- B gll: wave w stages bytes w*4096 + i*1024 + lane*16 (contiguous) --
    const char* Bsrc = (const char*)Wt2 + (size_t)w * 4096 + (size_t)lane * 16;
    const unsigned Boff = (unsigned)(w * 4096 + lane * 16);

    auto stageB = [&](int kt) {
        const char* s = Bsrc + (size_t)kt * 32768;
        char* d = (char*)B_s[kt & 1] + Boff;
#pragma unroll
        for (int i = 0; i < 4; ++i)
            gll16(s + i * 1024, d + i * 1024);
    };
    auto loadA = [&](int kt, float4& r) {
        r = *(const float4*)(Ag + (size_t)kt * BK);
    };
    auto writeA = [&](int kt, const float4& r) {
        u32x2 pk;
        pk[0] = cvt2(r.x, r.y);
        pk[1] = cvt2(r.z, r.w);
        *(u32x2*)((char*)A_s[kt & 1] + awr) = pk;
    };

    // ---- fragment read addresses ----
    const int wm = w >> 2, wn = w & 3;          // 2M x 4N wave grid
    const int lr = lane & 15, g = lane >> 4;
    unsigned aAddr[2], bAddr[8];
#pragma unroll
    for (int m = 0; m < 2; ++m) {
        int r = wm * 32 + m * 16 + lr;
        aAddr[m] = (unsigned)(r * 64 + ((g ^ ((r >> 1) & 3)) << 4));
    }
#pragma unroll
    for (int n = 0; n < 8; ++n) {
        int c = wn * 128 + n * 16 + lr;
        bAddr[n] = (unsigned)(c * 64 + ((g ^ ((c >> 1) & 3)) << 4));
    }

    f32x4 acc[2][8] = {};

    auto compute = [&](int buf) {
        const char* Ac = (const char*)A_s[buf];
        const char* Bc = (const char*)B_s[buf];
        s16x8 af[2];
#pragma unroll
        for (int m = 0; m < 2; ++m) af[m] = *(const s16x8*)(Ac + aAddr[m]);
#pragma unroll
        for (int h = 0; h < 2; ++h) {
            s16x8 bfr[4];
#pragma unroll
            for (int n = 0; n < 4; ++n)
                bfr[n] = *(const s16x8*)(Bc + bAddr[h * 4 + n]);
            __builtin_amdgcn_s_setprio(1);
#pragma unroll
            for (int m = 0; m < 2; ++m)
#pragma unroll
                for (int n = 0; n < 4; ++n)
                    acc[m][h * 4 + n] = __builtin_amdgcn_mfma_f32_16x16x32_bf16(
                        af[m], bfr[n], acc[m][h * 4 + n], 0, 0, 0);
            __builtin_amdgcn_s_setprio(0);
        }
    };

    // ---- prologue: A(0) (regs), B(0) (gll), A(1) (regs) ----
    float4 rP, rE, rO;
    loadA(0, rP);
    stageB(0);
    loadA(1, rE);
    writeA(0, rP);                                  // compiler waits rP
    asm volatile("s_waitcnt vmcnt(1) lgkmcnt(0)" ::: "memory");  // B(0) landed
    __builtin_amdgcn_sched_barrier(0);
    __builtin_amdgcn_s_barrier();

    // ---- steady state: one barrier/step; B issued at top hides under MFMA --
    // step kt: stageB(kt+1) -> other buf; loadA(kt+2); writeA(kt+1);
    //          compute(kt); vmcnt(1) [B(kt+1) landed, A(kt+2) in flight]; bar.
#define STEP(KT_, RW_, RL_)                                                    \
    {                                                                          \
        stageB((KT_) + 1);                                                     \
        loadA((KT_) + 2, RL_);                                                 \
        writeA((KT_) + 1, RW_);                                                \
        compute((KT_) & 1);                                                    \
        asm volatile("s_waitcnt vmcnt(1) lgkmcnt(0)" ::: "memory");            \
        __builtin_amdgcn_sched_barrier(0);                                     \
        __builtin_amdgcn_s_barrier();                                          \
    }

    for (int kt = 0; kt < KT - 2; kt += 2) {
        STEP(kt, rE, rO);
        STEP(kt + 1, rO, rE);
    }
#undef STEP
    // kt = 62: stage B(63), write A(63) (in rE), no further A loads
    {
        stageB(KT - 1);
        writeA(KT - 1, rE);
        compute((KT - 2) & 1);
        asm volatile("s_waitcnt vmcnt(0) lgkmcnt(0)" ::: "memory");
        __builtin_amdgcn_sched_barrier(0);
        __builtin_amdgcn_s_barrier();
    }
    compute((KT - 1) & 1);

    // ---- epilogue: att[row] = sum_h relu(p + base[b(row),h]) * W_f[h] ----
    const int b0 = m0 / A_RG;
    const int b1 = min(b0 + 1, B_SZ - 1);
    float wfv[8], bs0[8], bs1[8];
#pragma unroll
    for (int n = 0; n < 8; ++n) {
        int col = wn * 128 + n * 16 + lr;
        wfv[n] = W_f[col];
        bs0[n] = base_g[(size_t)b0 * H_SZ + col];
        bs1[n] = base_g[(size_t)b1 * H_SZ + col];
    }
#pragma unroll
    for (int m = 0; m < 2; ++m) {
        float pj[4] = {0.f, 0.f, 0.f, 0.f};
#pragma unroll
        for (int j = 0; j < 4; ++j) {
            int row = wm * 32 + m * 16 + g * 4 + j;
            bool second = (m0 + row) >= (b0 + 1) * A_RG;
#pragma unroll
            for (int n = 0; n < 8; ++n) {
                float bsv = second ? bs1[n] : bs0[n];
                pj[j] += fmaxf(acc[m][n][j] + bsv, 0.f) * wfv[n];
            }
        }
#pragma unroll
        for (int j = 0; j < 4; ++j) {
            float s = pj[j];
            s += __shfl_xor(s, 1);
            s += __shfl_xor(s, 2);
            s += __shfl_xor(s, 4);
            s += __shfl_xor(s, 8);     // sum over the 16 lr-lanes of this row
            if (lr == 0) {
                int row = wm * 32 + m * 16 + g * 4 + j;
                att_part[wn][row] = s;  // unique writer per (wn,row)
            }
        }
    }
    __syncthreads();

    if (t < BM) {
        att_g[m0 + t] = att_part[0][t] + att_part[1][t] +
                        att_part[2][t] + att_part[3][t];
    }
}

// ---------------------------------------------------------------------------
// Kernel 4: softmax over A=196 + weighted sum. grid (2 d-halves, 256 b),
// block 256; thread t owns one f32x4 column group (1KB/wave coalesced).
// ---------------------------------------------------------------------------
__global__ __launch_bounds__(256) void k_ws(const float* __restrict__ imgs,
                                            const float* __restrict__ att_g,
                                            float* __restrict__ out) {
    __shared__ float alpha_s[A_RG];
    int b = blockIdx.y, dc = blockIdx.x;
    int t = threadIdx.x;

    if (t < 64) {
        float v[4], e[4];
        float mx = -1e30f;
#pragma unroll
        for (int i = 0; i < 4; ++i) {
            int r = i * 64 + t;
            v[i] = (r < A_RG) ? att_g[(size_t)b * A_RG + r] : -1e30f;
            mx = fmaxf(mx, v[i]);
        }
        for (int d = 1; d < 64; d <<= 1) mx = fmaxf(mx, __shfl_xor(mx, d));
        float sum = 0.f;
#pragma unroll
        for (int i = 0; i < 4; ++i) {
            int r = i * 64 + t;
            e[i] = (r < A_RG) ? __expf(v[i] - mx) : 0.f;
            sum += e[i];
        }
        for (int d = 1; d < 64; d <<= 1) sum += __shfl_xor(sum, d);
        float inv = 1.0f / sum;
#pragma unroll
        for (int i = 0; i < 4; ++i) {
            int r = i * 64 + t;
            if (r < A_RG) alpha_s[r] = e[i] * inv;
        }
    }
    __syncthreads();

    const float* ib = imgs + (size_t)b * A_RG * DVD + dc * 1024 + t * 4;
    f32x4 o0 = {}, o1 = {};
#pragma unroll 2
    for (int a = 0; a < A_RG; a += 2) {
        float al0 = alpha_s[a], al1 = alpha_s[a + 1];
        f32x4 v0 = *(const f32x4*)(ib + (size_t)a * DVD);
        f32x4 v1 = *(const f32x4*)(ib + (size_t)(a + 1) * DVD);
#pragma unroll
        for (int j = 0; j < 4; ++j) {
            o0[j] = fmaf(al0, v0[j], o0[j]);
            o1[j] = fmaf(al1, v1[j], o1[j]);
        }
    }
    f32x4 o;
#pragma unroll
    for (int j = 0; j < 4; ++j) o[j] = o0[j] + o1[j];
    *(f32x4*)(out + (size_t)b * DVD + dc * 1024 + t * 4) = o;
}

// ---------------------------------------------------------------------------
extern "C" void kernel_launch(void* const* d_in, const int* in_sizes, int n_in,
                              void* d_out, int out_size, void* d_ws, size_t ws_size,
                              hipStream_t stream) {
    const float* h_att   = (const float*)d_in[0];
    const float* prev_h2 = (const float*)d_in[1];
    const float* imgs    = (const float*)d_in[2];
    const float* W_v     = (const float*)d_in[3];
    const float* b_v     = (const float*)d_in[4];
    const float* W_ha    = (const float*)d_in[5];
    const float* b_ha    = (const float*)d_in[6];
    const float* W_hv    = (const float*)d_in[7];
    const float* b_hv    = (const float*)d_in[8];
    const float* W_f     = (const float*)d_in[9];
    // d_in[10] = b_f: softmax-invariant additive constant -> unused

    // ws layout: [0,2MB) Wt2 bf16 [64][512][32] (k-tile-major, pre-swizzled);
    //            [2MB,+512KB) base fp32 [256][512]; then att fp32 [50176]
    unsigned short* Wt2 = (unsigned short*)d_ws;
    float* base_g = (float*)((char*)d_ws + (size_t)DVD * H_SZ * 2);
    float* att_g  = (float*)((char*)d_ws + (size_t)DVD * H_SZ * 2 + (size_t)B_SZ * H_SZ * 4);
    float* out = (float*)d_out;

    hipLaunchKernelGGL(k_prepW, dim3(256), dim3(256), 0, stream, W_v, Wt2);
    hipLaunchKernelGGL(k_base, dim3(256), dim3(256), 0, stream,
                       h_att, prev_h2, W_ha, b_ha, W_hv, b_hv, b_v, base_g);
    hipLaunchKernelGGL(k_gemm, dim3(M_TOT / BM), dim3(512), 0, stream,
                       imgs, Wt2, base_g, W_f, att_g);
    hipLaunchKernelGGL(k_ws, dim3(2, B_SZ), dim3(256), 0, stream,
                       imgs, att_g, out);
}